// Round 1
// baseline (950.007 us; speedup 1.0000x reference)
//
#include <hip/hip_runtime.h>
#include <hip/hip_bf16.h>

typedef __attribute__((ext_vector_type(4))) float  f4;
typedef __attribute__((ext_vector_type(8))) short  s8;
typedef __attribute__((ext_vector_type(4))) short  s4;

#define MFMA16(A,B,C) __builtin_amdgcn_mfma_f32_16x16x32_bf16((A),(B),(C),0,0,0)

__device__ __forceinline__ short f2bf(float f) {
  unsigned u = __float_as_uint(f);
  u = (u + 0x7fffu + ((u >> 16) & 1u)) >> 16;   // RNE
  return (short)u;
}

__device__ __forceinline__ f4 f4zero() { f4 z; z[0]=0.f; z[1]=0.f; z[2]=0.f; z[3]=0.f; return z; }

// ---------------- prep: weight bf16 conversion + relative-position bias ----------------
__global__ __launch_bounds__(256) void prep_kernel(
    const float* __restrict__ qkv_w, const float* __restrict__ proj_w,
    const float* __restrict__ table,
    short* __restrict__ wqkv, short* __restrict__ wproj, float* __restrict__ biasf)
{
  int idx = blockIdx.x * 256 + threadIdx.x;
  if (idx < 196608) {
    wqkv[idx] = f2bf(qkv_w[idx]);
  } else if (idx < 262144) {
    int t = idx - 196608;
    wproj[t] = f2bf(proj_w[t]);
  } else {
    int t = idx - 262144;                 // [0, 32768): h*4096 + i*64 + j
    int h = t >> 12, i = (t >> 6) & 63, j = t & 63;
    int ridx = ((i >> 3) - (j >> 3) + 7) * 15 + ((i & 7) - (j & 7) + 7);
    biasf[t] = table[ridx * 8 + h];
  }
}

// ---------------- fused window attention ----------------
// LDS strides (shorts). Chosen for 16B row alignment + <=2-way bank conflicts.
#define LDQ 40    // X / Q / K rows (32 data + 8 pad)
#define LDV 72    // Vt rows (64 data + 8 pad)
#define LDP 72    // P rows
#define LDO 264   // Olds rows (256 data + 8 pad)

__global__ __launch_bounds__(256, 2) void fused_kernel(
    const float* __restrict__ x, const float* __restrict__ mask,
    const float* __restrict__ qkv_b, const float* __restrict__ proj_b,
    const short* __restrict__ wqkv, const short* __restrict__ wproj,
    const float* __restrict__ biasf, float* __restrict__ out)
{
  __shared__ __align__(16) char smem[64512];
  short* Xs = (short*)smem;                                 // [64][40]
  const int tid  = threadIdx.x;
  const int lane = tid & 63;
  const int wv   = tid >> 6;          // wave 0..3
  const int m16  = lane & 15;
  const int quad = lane >> 4;
  const int b    = blockIdx.x;
  const float* xg = x + (size_t)b * 16384;

  short* Qs = (short*)(smem + 5120 + wv * 14848);           // [64][40]
  short* Ks = Qs + 2560;                                    // [64][40]
  short* Vt = Ks + 2560;                                    // [32][72]
  short* Ps = Qs;                                           // [64][72] overlay on Qs+Ks

  f4 oacc[2][2][4];                                         // [round][td][ti]
  float linvs[2][4];
  const float scale = 0.17677669529663687f;                 // 32^-0.5

  for (int rnd = 0; rnd < 2; ++rnd) {
    const int h = wv + rnd * 4;

    // ---- qkv GEMM for head h: Y[64][96] = X[64][256] * Wq^T ----
    f4 acc[3][2][4];
    #pragma unroll
    for (int s = 0; s < 3; ++s)
      #pragma unroll
      for (int tn = 0; tn < 2; ++tn)
        #pragma unroll
        for (int ti = 0; ti < 4; ++ti) acc[s][tn][ti] = f4zero();

    for (int ks = 0; ks < 8; ++ks) {
      __syncthreads();
      {   // stage X chunk [64][32] fp32 -> bf16 LDS; thread t: row=t>>2, 8 cols
        int row = tid >> 2, c0 = (tid & 3) * 8;
        const f4* src = (const f4*)(xg + row * 256 + ks * 32 + c0);
        f4 a = src[0], c = src[1];
        s8 v;
        v[0]=f2bf(a[0]); v[1]=f2bf(a[1]); v[2]=f2bf(a[2]); v[3]=f2bf(a[3]);
        v[4]=f2bf(c[0]); v[5]=f2bf(c[1]); v[6]=f2bf(c[2]); v[7]=f2bf(c[3]);
        *(s8*)&Xs[row * LDQ + c0] = v;
      }
      __syncthreads();
      s8 af[4];
      #pragma unroll
      for (int ti = 0; ti < 4; ++ti)
        af[ti] = *(const s8*)&Xs[(m16 + 16*ti) * LDQ + quad*8];
      #pragma unroll
      for (int s = 0; s < 3; ++s)
        #pragma unroll
        for (int tn = 0; tn < 2; ++tn) {
          const s8 bf = *(const s8*)&wqkv[(size_t)(s*256 + h*32 + tn*16 + m16) * 256 + ks*32 + quad*8];
          #pragma unroll
          for (int ti = 0; ti < 4; ++ti)
            acc[s][tn][ti] = MFMA16(af[ti], bf, acc[s][tn][ti]);
        }
    }

    // ---- epilogue: +bias, q*=scale, write Q,K row-major and V transposed ----
    #pragma unroll
    for (int s = 0; s < 3; ++s)
      #pragma unroll
      for (int tn = 0; tn < 2; ++tn) {
        float bias = qkv_b[s*256 + h*32 + tn*16 + m16];
        #pragma unroll
        for (int ti = 0; ti < 4; ++ti) {
          f4 v = acc[s][tn][ti];
          v[0]+=bias; v[1]+=bias; v[2]+=bias; v[3]+=bias;
          if (s == 0) { v[0]*=scale; v[1]*=scale; v[2]*=scale; v[3]*=scale; }
          int tok0 = ti*16 + quad*4;
          if (s < 2) {
            short* dst = (s == 0 ? Qs : Ks);
            int d = tn*16 + m16;
            dst[(tok0+0)*LDQ + d] = f2bf(v[0]);
            dst[(tok0+1)*LDQ + d] = f2bf(v[1]);
            dst[(tok0+2)*LDQ + d] = f2bf(v[2]);
            dst[(tok0+3)*LDQ + d] = f2bf(v[3]);
          } else {
            s4 vv; vv[0]=f2bf(v[0]); vv[1]=f2bf(v[1]); vv[2]=f2bf(v[2]); vv[3]=f2bf(v[3]);
            *(s4*)&Vt[(tn*16 + m16) * LDV + tok0] = vv;   // Vt[d][tok]
          }
        }
      }
    __syncthreads();

    // ---- S^T = K * Q^T (NT trick: both frags row-major [tok][d]) ----
    s8 qf[4], kf[4];
    #pragma unroll
    for (int t = 0; t < 4; ++t) {
      qf[t] = *(const s8*)&Qs[(m16 + 16*t) * LDQ + quad*8];
      kf[t] = *(const s8*)&Ks[(m16 + 16*t) * LDQ + quad*8];
    }
    f4 st[4][4];   // st[tjr][tic][p] = S[i=tic*16+m16][j=tjr*16+quad*4+p]
    #pragma unroll
    for (int tjr = 0; tjr < 4; ++tjr)
      #pragma unroll
      for (int tic = 0; tic < 4; ++tic)
        st[tjr][tic] = MFMA16(kf[tjr], qf[tic], f4zero());

    // bias + mask (float4 loads, j-contiguous thanks to S^T layout)
    const float* maskw = mask + (size_t)(b & 63) * 4096;
    #pragma unroll
    for (int tic = 0; tic < 4; ++tic) {
      int i = tic*16 + m16;
      #pragma unroll
      for (int tjr = 0; tjr < 4; ++tjr) {
        int j0 = tjr*16 + quad*4;
        f4 bb = *(const f4*)&biasf[(h*64 + i)*64 + j0];
        f4 mm = *(const f4*)&maskw[i*64 + j0];
        st[tjr][tic] += bb + mm;
      }
    }

    // ---- softmax over j (16 local values + xor16 + xor32) ----
    float linv[4];
    #pragma unroll
    for (int tic = 0; tic < 4; ++tic) {
      float mx = -1e30f;
      #pragma unroll
      for (int tjr = 0; tjr < 4; ++tjr)
        #pragma unroll
        for (int p = 0; p < 4; ++p) mx = fmaxf(mx, st[tjr][tic][p]);
      mx = fmaxf(mx, __shfl_xor(mx, 16, 64));
      mx = fmaxf(mx, __shfl_xor(mx, 32, 64));
      float sum = 0.f;
      #pragma unroll
      for (int tjr = 0; tjr < 4; ++tjr)
        #pragma unroll
        for (int p = 0; p < 4; ++p) {
          float e = exp2f((st[tjr][tic][p] - mx) * 1.4426950408889634f);
          st[tjr][tic][p] = e;
          sum += e;
        }
      sum += __shfl_xor(sum, 16, 64);
      sum += __shfl_xor(sum, 32, 64);
      linv[tic] = 1.f / sum;
      linvs[rnd][tic] = linv[tic];
    }

    // ---- write P (unnormalized exp) to LDS, b64-packed ----
    #pragma unroll
    for (int tic = 0; tic < 4; ++tic) {
      int i = tic*16 + m16;
      #pragma unroll
      for (int tjr = 0; tjr < 4; ++tjr) {
        int j0 = tjr*16 + quad*4;
        s4 pv;
        pv[0]=f2bf(st[tjr][tic][0]); pv[1]=f2bf(st[tjr][tic][1]);
        pv[2]=f2bf(st[tjr][tic][2]); pv[3]=f2bf(st[tjr][tic][3]);
        *(s4*)&Ps[i*LDP + j0] = pv;
      }
    }
    __syncthreads();

    // ---- O^T = Vt * P^T ----
    s8 vtf[2][2], pf[4][2];
    #pragma unroll
    for (int td = 0; td < 2; ++td)
      #pragma unroll
      for (int kk = 0; kk < 2; ++kk)
        vtf[td][kk] = *(const s8*)&Vt[(m16 + 16*td)*LDV + kk*32 + quad*8];
    #pragma unroll
    for (int ti = 0; ti < 4; ++ti)
      #pragma unroll
      for (int kk = 0; kk < 2; ++kk)
        pf[ti][kk] = *(const s8*)&Ps[(m16 + 16*ti)*LDP + kk*32 + quad*8];
    #pragma unroll
    for (int td = 0; td < 2; ++td)
      #pragma unroll
      for (int ti = 0; ti < 4; ++ti) {
        f4 o = MFMA16(vtf[td][0], pf[ti][0], f4zero());
        o = MFMA16(vtf[td][1], pf[ti][1], o);
        float li = linv[ti];
        o[0]*=li; o[1]*=li; o[2]*=li; o[3]*=li;
        oacc[rnd][td][ti] = o;
      }
  } // rounds

  // ---- gather all heads' O into shared Olds [64][256] bf16 ----
  __syncthreads();
  short* Olds = (short*)smem;   // overlays Xs + wave0/1 areas (all dead now)
  #pragma unroll
  for (int rnd = 0; rnd < 2; ++rnd) {
    int h = wv + rnd*4;
    #pragma unroll
    for (int td = 0; td < 2; ++td)
      #pragma unroll
      for (int ti = 0; ti < 4; ++ti) {
        int i  = m16 + 16*ti;
        int d0 = h*32 + td*16 + quad*4;
        f4 o = oacc[rnd][td][ti];
        s4 ov; ov[0]=f2bf(o[0]); ov[1]=f2bf(o[1]); ov[2]=f2bf(o[2]); ov[3]=f2bf(o[3]);
        *(s4*)&Olds[i*LDO + d0] = ov;
      }
  }
  __syncthreads();

  // ---- proj GEMM: out[64][256] = Olds * projW^T + proj_b ----
  f4 pacc[4][4];
  #pragma unroll
  for (int tn = 0; tn < 4; ++tn)
    #pragma unroll
    for (int ti = 0; ti < 4; ++ti) pacc[tn][ti] = f4zero();

  for (int ks = 0; ks < 8; ++ks) {
    s8 af[4];
    #pragma unroll
    for (int ti = 0; ti < 4; ++ti)
      af[ti] = *(const s8*)&Olds[(m16 + 16*ti)*LDO + ks*32 + quad*8];
    #pragma unroll
    for (int tn = 0; tn < 4; ++tn) {
      const s8 bf = *(const s8*)&wproj[(size_t)(wv*64 + tn*16 + m16)*256 + ks*32 + quad*8];
      #pragma unroll
      for (int ti = 0; ti < 4; ++ti)
        pacc[tn][ti] = MFMA16(af[ti], bf, pacc[tn][ti]);
    }
  }

  float* outb = out + (size_t)b * 16384;
  #pragma unroll
  for (int tn = 0; tn < 4; ++tn) {
    int c = wv*64 + tn*16 + m16;
    float pb = proj_b[c];
    #pragma unroll
    for (int ti = 0; ti < 4; ++ti) {
      int i0 = ti*16 + quad*4;
      f4 v = pacc[tn][ti];
      outb[(size_t)(i0+0)*256 + c] = v[0] + pb;
      outb[(size_t)(i0+1)*256 + c] = v[1] + pb;
      outb[(size_t)(i0+2)*256 + c] = v[2] + pb;
      outb[(size_t)(i0+3)*256 + c] = v[3] + pb;
    }
  }
}

extern "C" void kernel_launch(void* const* d_in, const int* in_sizes, int n_in,
                              void* d_out, int out_size, void* d_ws, size_t ws_size,
                              hipStream_t stream) {
  (void)in_sizes; (void)n_in; (void)out_size; (void)ws_size;
  const float* x      = (const float*)d_in[0];
  const float* mask   = (const float*)d_in[1];
  const float* qkv_w  = (const float*)d_in[2];
  const float* qkv_b  = (const float*)d_in[3];
  const float* proj_w = (const float*)d_in[4];
  const float* proj_b = (const float*)d_in[5];
  const float* table  = (const float*)d_in[6];
  // d_in[7] (rel_index) unused: index computed analytically (dtype-safe).
  float* out = (float*)d_out;

  char* ws = (char*)d_ws;
  short* wqkv  = (short*)ws;                // 196608 bf16 = 393216 B
  short* wproj = (short*)(ws + 393216);     //  65536 bf16 = 131072 B
  float* biasf = (float*)(ws + 524288);     //  32768 f32  = 131072 B  (total 640 KB)

  prep_kernel<<<1152, 256, 0, stream>>>(qkv_w, proj_w, table, wqkv, wproj, biasf);
  fused_kernel<<<4096, 256, 0, stream>>>(x, mask, qkv_b, proj_b, wqkv, wproj, biasf, out);
}